// Round 11
// baseline (305.700 us; speedup 1.0000x reference)
//
#include <hip/hip_runtime.h>
#include <hip/hip_cooperative_groups.h>
#include <math.h>

namespace cg = cooperative_groups;

#define HDIM 4096
#define HK 16
#define DK 256
#define VE 512
#define VD 8192
#define NCHUNK 16
#define DPC 16
#define EPS 1e-6f

// workspace float offsets
#define OFF_Q    0                        // 4096
#define OFF_K    4096                     // 4096
#define OFF_V    8192                     // 8192
#define OFF_AB   16384                    // 32
#define OFF_KQ   16416                    // 16
#define OFF_OUT  16432                    // 8192
#define OFF_PQ   24624                    // 16*VD
#define OFF_PK   (24624 + NCHUNK*VD)

typedef float f4_t __attribute__((ext_vector_type(4)));

__device__ __forceinline__ float sigmoidf_(float x) { return 1.f / (1.f + __expf(-x)); }
__device__ __forceinline__ float siluf_(float x)    { return x / (1.f + __expf(-x)); }

// ================= Cooperative mega-kernel: 512 blocks x 256 =================
// 2 blocks/CU needed, 4 blocks/CU capacity (VGPR<=128) -> 2x margin vs the
// R9 failure at 1024 blocks. Phases: 1) Wq+Wk+Wa/Wb GEMV; 2) Wv stream on
// 448 blocks || state partials on 64 blocks (which then take the Wv tail);
// 3) reduce+combine; 4) Wo GEMV.
__global__ __launch_bounds__(256, 4) void mega_kernel(
    const float* __restrict__ hvec,
    const float* __restrict__ Wq, const float* __restrict__ Wk,
    const float* __restrict__ Wv, const float* __restrict__ Wo,
    const float* __restrict__ Wa, const float* __restrict__ Wb,
    const float* __restrict__ qcw, const float* __restrict__ kcw,
    const float* __restrict__ vcw,
    const float* __restrict__ qc, const float* __restrict__ kc,
    const float* __restrict__ vc,
    const float* __restrict__ state,
    float* __restrict__ ws, float* __restrict__ dout) {
  cg::grid_group grid = cg::this_grid();
  const int tid  = threadIdx.x;
  const int wave = tid >> 6, lane = tid & 63;
  const int bid  = blockIdx.x;
  const int wid  = bid * 4 + wave;          // 0..2047
  const f4_t* h4 = (const f4_t*)hvec;

  __shared__ float q1s[DK], k1s[DK];
  __shared__ float red[3][4];

  // ---------- Phase 1: Wq+Wk rows (2 each per wave) + 32 A/B rows -----------
  for (int r = wid; r < 4096; r += 2048) {
    const f4_t* wq4 = (const f4_t*)(Wq + (size_t)r * HDIM);
    const f4_t* wk4 = (const f4_t*)(Wk + (size_t)r * HDIM);
    float aq = 0.f, ak = 0.f;
#pragma unroll
    for (int j = 0; j < 16; ++j) {
      f4_t hv = h4[j * 64 + lane];
      f4_t a  = __builtin_nontemporal_load(&wq4[j * 64 + lane]);
      f4_t b  = __builtin_nontemporal_load(&wk4[j * 64 + lane]);
      aq += a.x * hv.x + a.y * hv.y + a.z * hv.z + a.w * hv.w;
      ak += b.x * hv.x + b.y * hv.y + b.z * hv.z + b.w * hv.w;
    }
#pragma unroll
    for (int off = 32; off; off >>= 1) {
      aq += __shfl_xor(aq, off, 64);
      ak += __shfl_xor(ak, off, 64);
    }
    if (lane == 0) { ws[OFF_Q + r] = aq; ws[OFF_K + r] = ak; }
  }
  if ((wid & 63) == 0) {                    // 32 A/B rows on 32 distinct blocks
    int i = wid >> 6;                       // 0..31
    const float* Wr = (i < 16) ? (Wa + (size_t)i * HDIM)
                               : (Wb + (size_t)(i - 16) * HDIM);
    const f4_t* w4 = (const f4_t*)Wr;
    float acc = 0.f;
#pragma unroll
    for (int j = 0; j < 16; ++j) {
      f4_t w = __builtin_nontemporal_load(&w4[j * 64 + lane]);
      f4_t hv = h4[j * 64 + lane];
      acc += w.x * hv.x + w.y * hv.y + w.z * hv.z + w.w * hv.w;
    }
#pragma unroll
    for (int off = 32; off; off >>= 1) acc += __shfl_xor(acc, off, 64);
    if (lane == 0) ws[OFF_AB + i] = acc;
  }
  grid.sync();

  // ---- Phase 2: Wv[0,7680) on blocks 0..447 || state on blocks 448..511 ----
  if (bid < 448) {
    for (int r = wid; r < 7680; r += 1792) {
      const f4_t* w4 = (const f4_t*)(Wv + (size_t)r * HDIM);
      float acc = 0.f;
#pragma unroll
      for (int j = 0; j < 16; ++j) {
        f4_t w = __builtin_nontemporal_load(&w4[j * 64 + lane]);
        f4_t hv = h4[j * 64 + lane];
        acc += w.x * hv.x + w.y * hv.y + w.z * hv.z + w.w * hv.w;
      }
#pragma unroll
      for (int off = 32; off; off >>= 1) acc += __shfl_xor(acc, off, 64);
      if (lane == 0) ws[OFF_V + r] = acc;
    }
  } else {
    const int bb = bid - 448;       // 0..63
    const int hh = bb >> 2;         // head 0..15
    const int cq = bb & 3;          // chunk quad -> chunks 4*cq..4*cq+3
    {
      int i = hh * DK + tid;
      float q1 = qc[i*3+0]*qcw[i*4+0] + qc[i*3+1]*qcw[i*4+1] + qc[i*3+2]*qcw[i*4+2]
               + ws[OFF_Q + i]*qcw[i*4+3];
      q1 = siluf_(q1);
      float k1 = kc[i*3+0]*kcw[i*4+0] + kc[i*3+1]*kcw[i*4+1] + kc[i*3+2]*kcw[i*4+2]
               + ws[OFF_K + i]*kcw[i*4+3];
      k1 = siluf_(k1);
      float a = q1 * q1, b = k1 * k1, c = q1 * k1;
#pragma unroll
      for (int off = 32; off; off >>= 1) {
        a += __shfl_xor(a, off, 64);
        b += __shfl_xor(b, off, 64);
        c += __shfl_xor(c, off, 64);
      }
      if (lane == 0) { red[0][wave] = a; red[1][wave] = b; red[2][wave] = c; }
      __syncthreads();
      float ssq = red[0][0] + red[0][1] + red[0][2] + red[0][3];
      float ssk = red[1][0] + red[1][1] + red[1][2] + red[1][3];
      float skq = red[2][0] + red[2][1] + red[2][2] + red[2][3];
      float rq = rsqrtf(ssq + EPS), rk = rsqrtf(ssk + EPS);
      q1s[tid] = q1 * rq;           // normalized
      k1s[tid] = k1 * rk;
      if (cq == 0 && tid == 0) ws[OFF_KQ + hh] = skq * rq * rk;
      __syncthreads();
    }
#pragma unroll
    for (int cc = 0; cc < 4; ++cc) {
      int c = cq * 4 + cc;
      float aq0 = 0.f, aq1 = 0.f, ak0 = 0.f, ak1 = 0.f;
#pragma unroll
      for (int t = 0; t < DPC; ++t) {
        int d = c * DPC + t;
        const float* sp = state + ((size_t)(hh * DK + d)) * VE;
        float s0 = __builtin_nontemporal_load(sp + tid);
        float s1 = __builtin_nontemporal_load(sp + 256 + tid);
        aq0 += s0 * q1s[d]; ak0 += s0 * k1s[d];
        aq1 += s1 * q1s[d]; ak1 += s1 * k1s[d];
      }
      ws[OFF_PQ + c * VD + hh * VE + tid]       = aq0;
      ws[OFF_PQ + c * VD + hh * VE + 256 + tid] = aq1;
      ws[OFF_PK + c * VD + hh * VE + tid]       = ak0;
      ws[OFF_PK + c * VD + hh * VE + 256 + tid] = ak1;
    }
    // Wv tail rows [7680, 8192): 256 waves here, 2 rows each
    int swid = bb * 4 + wave;       // 0..255
#pragma unroll
    for (int rr = 0; rr < 2; ++rr) {
      int r = 7680 + swid * 2 + rr;
      const f4_t* w4 = (const f4_t*)(Wv + (size_t)r * HDIM);
      float acc = 0.f;
#pragma unroll
      for (int j = 0; j < 16; ++j) {
        f4_t w = __builtin_nontemporal_load(&w4[j * 64 + lane]);
        f4_t hv = h4[j * 64 + lane];
        acc += w.x * hv.x + w.y * hv.y + w.z * hv.z + w.w * hv.w;
      }
#pragma unroll
      for (int off = 32; off; off >>= 1) acc += __shfl_xor(acc, off, 64);
      if (lane == 0) ws[OFF_V + r] = acc;
    }
  }
  grid.sync();

  // -------- Phase 3: reduce 16 partials + v-conv/silu + combine -> out ------
  {
    int col = bid * 16 + (tid >> 4);  // 16 cols/block, 8192 total
    int j   = tid & 15;               // chunk index
    float pq = ws[OFF_PQ + j * VD + col];
    float pk = ws[OFF_PK + j * VD + col];
#pragma unroll
    for (int off = 8; off; off >>= 1) {
      pq += __shfl_xor(pq, off, 16);
      pk += __shfl_xor(pk, off, 16);
    }
    if (j == 0) {
      int hh = col >> 9;
      float v1 = vc[col*3+0]*vcw[col*4+0] + vc[col*3+1]*vcw[col*4+1] + vc[col*3+2]*vcw[col*4+2]
               + ws[OFF_V + col]*vcw[col*4+3];
      float vh  = siluf_(v1);
      float aa  = sigmoidf_(ws[OFF_AB + hh]);
      float bb2 = sigmoidf_(ws[OFF_AB + 16 + hh]);
      float kq  = ws[OFF_KQ + hh];
      ws[OFF_OUT + col] = aa * pq + bb2 * kq * (vh - aa * pk);
    }
  }
  grid.sync();

  // ---------------- Phase 4: Wo GEMV (2 rows per wave) ----------------------
  for (int r = wid; r < 4096; r += 2048) {
    const f4_t* r4 = (const f4_t*)(Wo + (size_t)r * VD);
    const f4_t* o4 = (const f4_t*)(ws + OFF_OUT);
    float acc = 0.f;
#pragma unroll
    for (int j = 0; j < 32; ++j) {
      f4_t w  = __builtin_nontemporal_load(&r4[j * 64 + lane]);
      f4_t ov = o4[j * 64 + lane];
      acc += w.x * ov.x + w.y * ov.y + w.z * ov.z + w.w * ov.w;
    }
#pragma unroll
    for (int off = 32; off; off >>= 1) acc += __shfl_xor(acc, off, 64);
    if (lane == 0) dout[r] = acc;
  }
}

// ===================== Fallback: proven 4-kernel path (~73us) ================
__global__ __launch_bounds__(256) void k1_gemv_all(
    const float* __restrict__ hvec,
    const float* __restrict__ Wq, const float* __restrict__ Wk,
    const float* __restrict__ Wv, const float* __restrict__ Wa,
    const float* __restrict__ Wb, float* __restrict__ ws) {
  int tid = threadIdx.x;
  int wave = tid >> 6, lane = tid & 63;
  int row = blockIdx.x * 4 + wave;
  if (row >= 16416) return;

  const f4_t* w4; float* outp;
  if (row < 4096)       { w4 = (const f4_t*)(Wq + (size_t)row * HDIM);            outp = ws + OFF_Q + row; }
  else if (row < 8192)  { int r = row - 4096;  w4 = (const f4_t*)(Wk + (size_t)r * HDIM); outp = ws + OFF_K + r; }
  else if (row < 16384) { int r = row - 8192;  w4 = (const f4_t*)(Wv + (size_t)r * HDIM); outp = ws + OFF_V + r; }
  else if (row < 16400) { int r = row - 16384; w4 = (const f4_t*)(Wa + (size_t)r * HDIM); outp = ws + OFF_AB + r; }
  else                  { int r = row - 16400; w4 = (const f4_t*)(Wb + (size_t)r * HDIM); outp = ws + OFF_AB + 16 + r; }

  const f4_t* h4 = (const f4_t*)hvec;
  float acc = 0.f;
#pragma unroll
  for (int j = 0; j < 16; ++j) {
    f4_t w  = __builtin_nontemporal_load(&w4[j * 64 + lane]);
    f4_t hv = h4[j * 64 + lane];
    acc += w.x * hv.x + w.y * hv.y + w.z * hv.z + w.w * hv.w;
  }
#pragma unroll
  for (int off = 32; off; off >>= 1) acc += __shfl_xor(acc, off, 64);
  if (lane == 0) *outp = acc;
}

__global__ __launch_bounds__(512) void kB_state(
    const float* __restrict__ qcw, const float* __restrict__ kcw,
    const float* __restrict__ qc,  const float* __restrict__ kc,
    const float* __restrict__ state, float* __restrict__ ws) {
  int hh = blockIdx.x >> 4;
  int c  = blockIdx.x & 15;
  int tid = threadIdx.x;
  __shared__ float q1s[DK], k1s[DK];
  __shared__ float red[3][8];

  float a = 0.f, b = 0.f, cc = 0.f;
  if (tid < DK) {
    int i = hh * DK + tid;
    float q1 = qc[i*3+0]*qcw[i*4+0] + qc[i*3+1]*qcw[i*4+1] + qc[i*3+2]*qcw[i*4+2]
             + ws[OFF_Q + i]*qcw[i*4+3];
    q1 = siluf_(q1);
    float k1 = kc[i*3+0]*kcw[i*4+0] + kc[i*3+1]*kcw[i*4+1] + kc[i*3+2]*kcw[i*4+2]
             + ws[OFF_K + i]*kcw[i*4+3];
    k1 = siluf_(k1);
    q1s[tid] = q1; k1s[tid] = k1;
    a = q1 * q1; b = k1 * k1; cc = q1 * k1;
  }
#pragma unroll
  for (int off = 32; off; off >>= 1) {
    a  += __shfl_xor(a, off, 64);
    b  += __shfl_xor(b, off, 64);
    cc += __shfl_xor(cc, off, 64);
  }
  int wave = tid >> 6, lane = tid & 63;
  if (lane == 0) { red[0][wave] = a; red[1][wave] = b; red[2][wave] = cc; }
  __syncthreads();
  float ssq = 0.f, ssk = 0.f, skq = 0.f;
#pragma unroll
  for (int w = 0; w < 8; ++w) { ssq += red[0][w]; ssk += red[1][w]; skq += red[2][w]; }
  float rq = rsqrtf(ssq + EPS), rk = rsqrtf(ssk + EPS);
  if (c == 0 && tid == 0) ws[OFF_KQ + hh] = skq * rq * rk;

  int vv = tid;
  int d0 = c * DPC;
  float aq = 0.f, ak = 0.f;
#pragma unroll
  for (int t = 0; t < DPC; ++t) {
    int d = d0 + t;
    float s = __builtin_nontemporal_load(state + ((size_t)(hh * DK + d)) * VE + vv);
    aq += s * q1s[d];
    ak += s * k1s[d];
  }
  ws[OFF_PQ + c * VD + hh * VE + vv] = aq * rq;
  ws[OFF_PK + c * VD + hh * VE + vv] = ak * rk;
}

__global__ __launch_bounds__(128) void kC_combine(
    const float* __restrict__ vcw, const float* __restrict__ vc,
    float* __restrict__ ws) {
  int hh = blockIdx.x >> 2;
  int vv = (blockIdx.x & 3) * 128 + threadIdx.x;
  int col = hh * VE + vv;

  float Sq = 0.f, Sk = 0.f;
#pragma unroll
  for (int c = 0; c < NCHUNK; ++c) {
    Sq += ws[OFF_PQ + c * VD + col];
    Sk += ws[OFF_PK + c * VD + col];
  }
  float v1 = vc[col*3+0]*vcw[col*4+0] + vc[col*3+1]*vcw[col*4+1] + vc[col*3+2]*vcw[col*4+2]
           + ws[OFF_V + col]*vcw[col*4+3];
  float vh = siluf_(v1);
  float a  = sigmoidf_(ws[OFF_AB + hh]);
  float bb = sigmoidf_(ws[OFF_AB + 16 + hh]);
  float kq = ws[OFF_KQ + hh];
  ws[OFF_OUT + col] = a * Sq + bb * kq * (vh - a * Sk);
}

__global__ __launch_bounds__(256) void kD_gemv_out(
    const float* __restrict__ Wo, const float* __restrict__ ws,
    float* __restrict__ dout) {
  int tid = threadIdx.x;
  int wave = tid >> 6, lane = tid & 63;
  int row = blockIdx.x * 4 + wave;
  const f4_t* r4 = (const f4_t*)(Wo + (size_t)row * VD);
  const f4_t* o4 = (const f4_t*)(ws + OFF_OUT);

  float acc = 0.f;
#pragma unroll
  for (int j = 0; j < 32; ++j) {
    f4_t w  = __builtin_nontemporal_load(&r4[j * 64 + lane]);
    f4_t ov = o4[j * 64 + lane];
    acc += w.x * ov.x + w.y * ov.y + w.z * ov.z + w.w * ov.w;
  }
#pragma unroll
  for (int off = 32; off; off >>= 1) acc += __shfl_xor(acc, off, 64);
  if (lane == 0) dout[row] = acc;
}

extern "C" void kernel_launch(void* const* d_in, const int* in_sizes, int n_in,
                              void* d_out, int out_size, void* d_ws, size_t ws_size,
                              hipStream_t stream) {
  const float* hvec = (const float*)d_in[0];
  const float* Wq   = (const float*)d_in[1];
  const float* Wk   = (const float*)d_in[2];
  const float* Wv   = (const float*)d_in[3];
  const float* Wo   = (const float*)d_in[4];
  const float* Wa   = (const float*)d_in[5];
  const float* Wb   = (const float*)d_in[6];
  const float* qcw  = (const float*)d_in[7];
  const float* kcw  = (const float*)d_in[8];
  const float* vcw  = (const float*)d_in[9];
  const float* qc   = (const float*)d_in[10];
  const float* kc   = (const float*)d_in[11];
  const float* vc   = (const float*)d_in[12];
  const float* state= (const float*)d_in[13];
  float* ws  = (float*)d_ws;
  float* out = (float*)d_out;

  void* args[] = { (void*)&hvec, (void*)&Wq, (void*)&Wk, (void*)&Wv, (void*)&Wo,
                   (void*)&Wa, (void*)&Wb, (void*)&qcw, (void*)&kcw, (void*)&vcw,
                   (void*)&qc, (void*)&kc, (void*)&vc, (void*)&state,
                   (void*)&ws, (void*)&out };
  hipError_t e = hipLaunchCooperativeKernel((const void*)mega_kernel, dim3(512),
                                            dim3(256), args, 0, stream);
  if (e != hipSuccess) {
    // Fallback: proven 4-kernel pipeline.
    k1_gemv_all<<<4104, 256, 0, stream>>>(hvec, Wq, Wk, Wv, Wa, Wb, ws);
    kB_state<<<256, 512, 0, stream>>>(qcw, kcw, qc, kc, state, ws);
    kC_combine<<<64, 128, 0, stream>>>(vcw, vc, ws);
    kD_gemv_out<<<1024, 256, 0, stream>>>(Wo, ws, out);
  }
}

// Round 12
// 136.090 us; speedup vs baseline: 2.2463x; 2.2463x over previous
//
#include <hip/hip_runtime.h>
#include <math.h>

#define HDIM 4096
#define HK 16
#define DK 256
#define VE 512
#define VD 8192
#define NCHUNK 16
#define DPC 16
#define EPS 1e-6f

// workspace float offsets
#define OFF_Q    0                        // 4096
#define OFF_K    4096                     // 4096
#define OFF_V    8192                     // 8192
#define OFF_AB   16384                    // 32
#define OFF_KQ   16416                    // 16
#define OFF_OUT  16432                    // 8192
#define OFF_PQ   24624                    // 16*VD partial Sq
#define OFF_PK   (24624 + NCHUNK*VD)      // 16*VD partial Sk
#define OFF_CNT  (OFF_PK + NCHUNK*VD)     // 1 int: kB completion counter

typedef float f4_t __attribute__((ext_vector_type(4)));

__device__ __forceinline__ float sigmoidf_(float x) { return 1.f / (1.f + __expf(-x)); }
__device__ __forceinline__ float siluf_(float x)    { return x / (1.f + __expf(-x)); }

// ---------------- Kernel 1: fused GEMV over Wq/Wk/Wv/Wa/Wb -------------------
// R6 configuration exactly (best measured 73.0us): wave per row, 4 waves/block,
// caching loads. Also zero-inits the kB completion counter.
__global__ __launch_bounds__(256) void k1_gemv_all(
    const float* __restrict__ hvec,
    const float* __restrict__ Wq, const float* __restrict__ Wk,
    const float* __restrict__ Wv, const float* __restrict__ Wa,
    const float* __restrict__ Wb, float* __restrict__ ws) {
  if (blockIdx.x == 0 && threadIdx.x == 0) *(int*)(ws + OFF_CNT) = 0;

  int tid = threadIdx.x;
  int wave = tid >> 6, lane = tid & 63;
  int row = blockIdx.x * 4 + wave;
  if (row >= 16416) return;

  const f4_t* w4; float* outp;
  if (row < 4096)       { w4 = (const f4_t*)(Wq + (size_t)row * HDIM);            outp = ws + OFF_Q + row; }
  else if (row < 8192)  { int r = row - 4096;  w4 = (const f4_t*)(Wk + (size_t)r * HDIM); outp = ws + OFF_K + r; }
  else if (row < 16384) { int r = row - 8192;  w4 = (const f4_t*)(Wv + (size_t)r * HDIM); outp = ws + OFF_V + r; }
  else if (row < 16400) { int r = row - 16384; w4 = (const f4_t*)(Wa + (size_t)r * HDIM); outp = ws + OFF_AB + r; }
  else                  { int r = row - 16400; w4 = (const f4_t*)(Wb + (size_t)r * HDIM); outp = ws + OFF_AB + 16 + r; }

  const f4_t* h4 = (const f4_t*)hvec;
  float acc = 0.f;
#pragma unroll
  for (int j = 0; j < 16; ++j) {
    f4_t w  = w4[j * 64 + lane];
    f4_t hv = h4[j * 64 + lane];
    acc += w.x * hv.x + w.y * hv.y + w.z * hv.z + w.w * hv.w;
  }
#pragma unroll
  for (int off = 32; off; off >>= 1) acc += __shfl_xor(acc, off, 64);
  if (lane == 0) *outp = acc;
}

// ----- Kernel B: state partials + FUSED combine (last-block-done pattern) ----
// grid 256 = 16 heads x 16 chunks; 512 threads. After writing its partials,
// each block bumps a device-scope counter; the LAST block (release/acquire
// threadfences around the atomic) performs the former kC combine: reduce 16
// partials per column + v-conv/silu + sigmoid gates -> ws[OFF_OUT].
// No grid-wide spin (R11 lesson: spinning barriers cost ~50us/sync).
__global__ __launch_bounds__(512) void kB_state(
    const float* __restrict__ qcw, const float* __restrict__ kcw,
    const float* __restrict__ qc,  const float* __restrict__ kc,
    const float* __restrict__ vcw, const float* __restrict__ vc,
    const float* __restrict__ state, float* __restrict__ ws) {
  int hh = blockIdx.x >> 4;
  int c  = blockIdx.x & 15;
  int tid = threadIdx.x;
  __shared__ float q1s[DK], k1s[DK];
  __shared__ float red[3][8];
  __shared__ int lastFlag;

  float a = 0.f, b = 0.f, cc = 0.f;
  if (tid < DK) {
    int i = hh * DK + tid;
    float q1 = qc[i*3+0]*qcw[i*4+0] + qc[i*3+1]*qcw[i*4+1] + qc[i*3+2]*qcw[i*4+2]
             + ws[OFF_Q + i]*qcw[i*4+3];
    q1 = siluf_(q1);
    float k1 = kc[i*3+0]*kcw[i*4+0] + kc[i*3+1]*kcw[i*4+1] + kc[i*3+2]*kcw[i*4+2]
             + ws[OFF_K + i]*kcw[i*4+3];
    k1 = siluf_(k1);
    q1s[tid] = q1; k1s[tid] = k1;
    a = q1 * q1; b = k1 * k1; cc = q1 * k1;
  }
#pragma unroll
  for (int off = 32; off; off >>= 1) {
    a  += __shfl_xor(a, off, 64);
    b  += __shfl_xor(b, off, 64);
    cc += __shfl_xor(cc, off, 64);
  }
  int wave = tid >> 6, lane = tid & 63;
  if (lane == 0) { red[0][wave] = a; red[1][wave] = b; red[2][wave] = cc; }
  __syncthreads();
  float ssq = 0.f, ssk = 0.f, skq = 0.f;
#pragma unroll
  for (int w = 0; w < 8; ++w) { ssq += red[0][w]; ssk += red[1][w]; skq += red[2][w]; }
  float rq = rsqrtf(ssq + EPS), rk = rsqrtf(ssk + EPS);
  if (c == 0 && tid == 0) ws[OFF_KQ + hh] = skq * rq * rk;

  int vv = tid;
  int d0 = c * DPC;
  float aq = 0.f, ak = 0.f;
#pragma unroll
  for (int t = 0; t < DPC; ++t) {
    int d = d0 + t;
    float s = __builtin_nontemporal_load(state + ((size_t)(hh * DK + d)) * VE + vv);
    aq += s * q1s[d];
    ak += s * k1s[d];
  }
  ws[OFF_PQ + c * VD + hh * VE + vv] = aq * rq;
  ws[OFF_PK + c * VD + hh * VE + vv] = ak * rk;

  // ---- completion counter; last block does the combine ----
  __threadfence();                              // release partials device-wide
  if (tid == 0) {
    int old = atomicAdd((int*)(ws + OFF_CNT), 1);
    lastFlag = (old == 255);
  }
  __syncthreads();
  if (!lastFlag) return;
  __threadfence();                              // acquire other blocks' writes

  for (int col = tid; col < VD; col += 512) {
    float Sq = 0.f, Sk = 0.f;
#pragma unroll
    for (int cch = 0; cch < NCHUNK; ++cch) {
      Sq += ws[OFF_PQ + cch * VD + col];
      Sk += ws[OFF_PK + cch * VD + col];
    }
    int h2 = col >> 9;
    float v1 = vc[col*3+0]*vcw[col*4+0] + vc[col*3+1]*vcw[col*4+1] + vc[col*3+2]*vcw[col*4+2]
             + ws[OFF_V + col]*vcw[col*4+3];
    float vh  = siluf_(v1);
    float aa  = sigmoidf_(ws[OFF_AB + h2]);
    float bb  = sigmoidf_(ws[OFF_AB + 16 + h2]);
    float kq  = ws[OFF_KQ + h2];
    ws[OFF_OUT + col] = aa * Sq + bb * kq * (vh - aa * Sk);
  }
}

// --------------- Kernel D: output GEMV  d_out = Wo @ out ---------------------
// wave per row, 4 waves/block, 4096 rows. Wo non-temporal (R6 config).
__global__ __launch_bounds__(256) void kD_gemv_out(
    const float* __restrict__ Wo, const float* __restrict__ ws,
    float* __restrict__ dout) {
  int tid = threadIdx.x;
  int wave = tid >> 6, lane = tid & 63;
  int row = blockIdx.x * 4 + wave;
  const f4_t* r4 = (const f4_t*)(Wo + (size_t)row * VD);
  const f4_t* o4 = (const f4_t*)(ws + OFF_OUT);

  float acc = 0.f;
#pragma unroll
  for (int j = 0; j < 32; ++j) {
    f4_t w  = __builtin_nontemporal_load(&r4[j * 64 + lane]);
    f4_t ov = o4[j * 64 + lane];
    acc += w.x * ov.x + w.y * ov.y + w.z * ov.z + w.w * ov.w;
  }
#pragma unroll
  for (int off = 32; off; off >>= 1) acc += __shfl_xor(acc, off, 64);
  if (lane == 0) dout[row] = acc;
}

extern "C" void kernel_launch(void* const* d_in, const int* in_sizes, int n_in,
                              void* d_out, int out_size, void* d_ws, size_t ws_size,
                              hipStream_t stream) {
  const float* hvec = (const float*)d_in[0];
  const float* Wq   = (const float*)d_in[1];
  const float* Wk   = (const float*)d_in[2];
  const float* Wv   = (const float*)d_in[3];
  const float* Wo   = (const float*)d_in[4];
  const float* Wa   = (const float*)d_in[5];
  const float* Wb   = (const float*)d_in[6];
  const float* qcw  = (const float*)d_in[7];
  const float* kcw  = (const float*)d_in[8];
  const float* vcw  = (const float*)d_in[9];
  const float* qc   = (const float*)d_in[10];
  const float* kc   = (const float*)d_in[11];
  const float* vc   = (const float*)d_in[12];
  const float* state= (const float*)d_in[13];
  float* ws  = (float*)d_ws;
  float* out = (float*)d_out;

  k1_gemv_all<<<4104, 256, 0, stream>>>(hvec, Wq, Wk, Wv, Wa, Wb, ws);
  kB_state<<<256, 512, 0, stream>>>(qcw, kcw, qc, kc, vcw, vc, state, ws);
  kD_gemv_out<<<1024, 256, 0, stream>>>(Wo, ws, out);
}

// Round 13
// 73.359 us; speedup vs baseline: 4.1672x; 1.8551x over previous
//
#include <hip/hip_runtime.h>
#include <math.h>

#define HDIM 4096
#define HK 16
#define DK 256
#define VE 512
#define QK 4096
#define VD 8192
#define NCHUNK 16
#define DPC 16           // DK / NCHUNK
#define EPS 1e-6f

// workspace float offsets
#define OFF_Q    0                        // 4096 (q linear)
#define OFF_K    4096                     // 4096
#define OFF_V    8192                     // 8192
#define OFF_AB   16384                    // 32 (alpha_lin 16, beta_lin 16)
#define OFF_KQ   16416                    // 16  (<q_h, k_h> per head)
#define OFF_OUT  16432                    // 8192
#define OFF_PQ   24624                    // NCHUNK*VD = 131072 partial Sq
#define OFF_PK   (24624 + NCHUNK*VD)      // 131072 partial Sk

typedef float f4_t __attribute__((ext_vector_type(4)));

__device__ __forceinline__ float sigmoidf_(float x) { return 1.f / (1.f + __expf(-x)); }
__device__ __forceinline__ float siluf_(float x)    { return x / (1.f + __expf(-x)); }

// ---------------- Kernel 1: fused GEMV over Wq/Wk/Wv/Wa/Wb -------------------
// R6 configuration exactly (best measured: 73.0 us replay).
// wave per row, 4 waves/block, 16416 rows, caching loads.
__global__ __launch_bounds__(256) void k1_gemv_all(
    const float* __restrict__ hvec,
    const float* __restrict__ Wq, const float* __restrict__ Wk,
    const float* __restrict__ Wv, const float* __restrict__ Wa,
    const float* __restrict__ Wb, float* __restrict__ ws) {
  int tid = threadIdx.x;
  int wave = tid >> 6, lane = tid & 63;
  int row = blockIdx.x * 4 + wave;
  if (row >= 16416) return;

  const f4_t* w4; float* outp;
  if (row < 4096)       { w4 = (const f4_t*)(Wq + (size_t)row * HDIM);            outp = ws + OFF_Q + row; }
  else if (row < 8192)  { int r = row - 4096;  w4 = (const f4_t*)(Wk + (size_t)r * HDIM); outp = ws + OFF_K + r; }
  else if (row < 16384) { int r = row - 8192;  w4 = (const f4_t*)(Wv + (size_t)r * HDIM); outp = ws + OFF_V + r; }
  else if (row < 16400) { int r = row - 16384; w4 = (const f4_t*)(Wa + (size_t)r * HDIM); outp = ws + OFF_AB + r; }
  else                  { int r = row - 16400; w4 = (const f4_t*)(Wb + (size_t)r * HDIM); outp = ws + OFF_AB + 16 + r; }

  const f4_t* h4 = (const f4_t*)hvec;
  float acc = 0.f;
#pragma unroll
  for (int j = 0; j < 16; ++j) {
    f4_t w  = w4[j * 64 + lane];
    f4_t hv = h4[j * 64 + lane];
    acc += w.x * hv.x + w.y * hv.y + w.z * hv.z + w.w * hv.w;
  }
#pragma unroll
  for (int off = 32; off; off >>= 1) acc += __shfl_xor(acc, off, 64);
  if (lane == 0) *outp = acc;
}

// ------- Kernel B: state partials; per-head conv+silu+l2norm redundant -------
// grid 256 = 16 heads x 16 chunks; 512 threads (one per v column).
// state read once per iteration -> non-temporal.
__global__ __launch_bounds__(512) void kB_state(
    const float* __restrict__ qcw, const float* __restrict__ kcw,
    const float* __restrict__ qc,  const float* __restrict__ kc,
    const float* __restrict__ state, float* __restrict__ ws) {
  int hh = blockIdx.x >> 4;
  int c  = blockIdx.x & 15;
  int tid = threadIdx.x;
  __shared__ float q1s[DK], k1s[DK];
  __shared__ float red[3][8];

  float a = 0.f, b = 0.f, cc = 0.f;
  if (tid < DK) {
    int i = hh * DK + tid;
    float q1 = qc[i*3+0]*qcw[i*4+0] + qc[i*3+1]*qcw[i*4+1] + qc[i*3+2]*qcw[i*4+2]
             + ws[OFF_Q + i]*qcw[i*4+3];
    q1 = siluf_(q1);
    float k1 = kc[i*3+0]*kcw[i*4+0] + kc[i*3+1]*kcw[i*4+1] + kc[i*3+2]*kcw[i*4+2]
             + ws[OFF_K + i]*kcw[i*4+3];
    k1 = siluf_(k1);
    q1s[tid] = q1; k1s[tid] = k1;
    a = q1 * q1; b = k1 * k1; cc = q1 * k1;
  }
#pragma unroll
  for (int off = 32; off; off >>= 1) {
    a  += __shfl_xor(a, off, 64);
    b  += __shfl_xor(b, off, 64);
    cc += __shfl_xor(cc, off, 64);
  }
  int wave = tid >> 6, lane = tid & 63;
  if (lane == 0) { red[0][wave] = a; red[1][wave] = b; red[2][wave] = cc; }
  __syncthreads();
  float ssq = 0.f, ssk = 0.f, skq = 0.f;
#pragma unroll
  for (int w = 0; w < 8; ++w) { ssq += red[0][w]; ssk += red[1][w]; skq += red[2][w]; }
  float rq = rsqrtf(ssq + EPS), rk = rsqrtf(ssk + EPS);
  if (c == 0 && tid == 0) ws[OFF_KQ + hh] = skq * rq * rk;

  int vv = tid;
  int d0 = c * DPC;
  float aq = 0.f, ak = 0.f;
#pragma unroll
  for (int t = 0; t < DPC; ++t) {
    int d = d0 + t;
    float s = __builtin_nontemporal_load(state + ((size_t)(hh * DK + d)) * VE + vv);
    aq += s * q1s[d];
    ak += s * k1s[d];
  }
  ws[OFF_PQ + c * VD + hh * VE + vv] = aq * rq;
  ws[OFF_PK + c * VD + hh * VE + vv] = ak * rk;
}

// ------ Kernel C: reduce partials + v-conv/silu + sigmoid + combine ----------
// 64 blocks x 128 threads; thread -> (head hh, column vv)
__global__ __launch_bounds__(128) void kC_combine(
    const float* __restrict__ vcw, const float* __restrict__ vc,
    float* __restrict__ ws) {
  int hh = blockIdx.x >> 2;
  int vv = (blockIdx.x & 3) * 128 + threadIdx.x;
  int col = hh * VE + vv;

  float Sq = 0.f, Sk = 0.f;
#pragma unroll
  for (int c = 0; c < NCHUNK; ++c) {
    Sq += ws[OFF_PQ + c * VD + col];
    Sk += ws[OFF_PK + c * VD + col];
  }
  float v1 = vc[col*3+0]*vcw[col*4+0] + vc[col*3+1]*vcw[col*4+1] + vc[col*3+2]*vcw[col*4+2]
           + ws[OFF_V + col]*vcw[col*4+3];
  float vh = siluf_(v1);
  float a  = sigmoidf_(ws[OFF_AB + hh]);
  float bb = sigmoidf_(ws[OFF_AB + 16 + hh]);
  float kq = ws[OFF_KQ + hh];
  // out = a*Sq + b*kq*(vh - a*Sk)
  ws[OFF_OUT + col] = a * Sq + bb * kq * (vh - a * Sk);
}

// --------------- Kernel D: output GEMV  d_out = Wo @ out ---------------------
// wave per row, 4 waves/block, 4096 rows. Wo read once per iteration ->
// non-temporal (no L3 allocation churn).
__global__ __launch_bounds__(256) void kD_gemv_out(
    const float* __restrict__ Wo, const float* __restrict__ ws,
    float* __restrict__ dout) {
  int tid = threadIdx.x;
  int wave = tid >> 6, lane = tid & 63;
  int row = blockIdx.x * 4 + wave;
  const f4_t* r4 = (const f4_t*)(Wo + (size_t)row * VD);
  const f4_t* o4 = (const f4_t*)(ws + OFF_OUT);

  float acc = 0.f;
#pragma unroll
  for (int j = 0; j < 32; ++j) {
    f4_t w  = __builtin_nontemporal_load(&r4[j * 64 + lane]);
    f4_t ov = o4[j * 64 + lane];
    acc += w.x * ov.x + w.y * ov.y + w.z * ov.z + w.w * ov.w;
  }
#pragma unroll
  for (int off = 32; off; off >>= 1) acc += __shfl_xor(acc, off, 64);
  if (lane == 0) dout[row] = acc;
}

extern "C" void kernel_launch(void* const* d_in, const int* in_sizes, int n_in,
                              void* d_out, int out_size, void* d_ws, size_t ws_size,
                              hipStream_t stream) {
  const float* hvec = (const float*)d_in[0];
  const float* Wq   = (const float*)d_in[1];
  const float* Wk   = (const float*)d_in[2];
  const float* Wv   = (const float*)d_in[3];
  const float* Wo   = (const float*)d_in[4];
  const float* Wa   = (const float*)d_in[5];
  const float* Wb   = (const float*)d_in[6];
  const float* qcw  = (const float*)d_in[7];
  const float* kcw  = (const float*)d_in[8];
  const float* vcw  = (const float*)d_in[9];
  const float* qc   = (const float*)d_in[10];
  const float* kc   = (const float*)d_in[11];
  const float* vc   = (const float*)d_in[12];
  const float* state= (const float*)d_in[13];
  float* ws  = (float*)d_ws;
  float* out = (float*)d_out;

  k1_gemv_all<<<4104, 256, 0, stream>>>(hvec, Wq, Wk, Wv, Wa, Wb, ws);
  kB_state<<<256, 512, 0, stream>>>(qcw, kcw, qc, kc, state, ws);
  kC_combine<<<64, 128, 0, stream>>>(vcw, vc, ws);
  kD_gemv_out<<<1024, 256, 0, stream>>>(Wo, ws, out);
}